// Round 2
// baseline (566.898 us; speedup 1.0000x reference)
//
#include <hip/hip_runtime.h>

// MeshUnpool — transposed-gather formulation, v3.
//
// R2 direct gather was request-rate-bound (147M scattered 4B loads, 1.79 TB/s).
// R3 (v2): transpose feat -> featT[b][e][c] (512 B contiguous rows), gather
// whole rows, LDS-transpose to coalesced out stores. dur 988 -> 550 us.
// ~290 us of dur is harness-constant (ws poison fill + resets); our kernels
// sum to ~260 us vs ~175 us streaming floor.
//
// v3 changes (this round):
//  - gatherT: stage the [64 j][128 c] tile in TWO 64-channel halves
//    (tile[64][68] = 17.4 KB instead of 33.8 KB) -> ~8 blocks/CU instead of 4;
//    accumulators live in registers across the half barriers. Random-row read
//    latency hides much better across the phase barriers.
//  - gatherT: nontemporal out stores — out is write-once; keep featT (which
//    has 1.67x read reuse) resident in L2 instead.
//  - transpose: 64x64 tiles -> 256 B global segments both sides (was 128 B),
//    16.6 KB LDS, +1-pad conflict-free.
//
// Pipeline:
//   K1 build_map   : per-output-column {s0, s1, w0, w1}        (~9.2 MB ws)
//   K2 transpose   : feat[b][c][e] -> featT[b][e][c]           (ws)
//   K3 gatherT     : out[b][c][j] = w0*featT[b][s0][c] + w1*featT[b][s1][c]
// ws fallback: per-batch featT loop (24.6 MB), else R2 direct gather.

constexpr int B_     = 8;
constexpr int C_     = 128;
constexpr int E_OLD_ = 48000;
constexpr int U_     = 8000;
constexpr int E_NEW_ = E_OLD_ + 3 * U_;          // 72000
constexpr int T_PER_B = U_ + (E_OLD_ - 2 * U_);  // 40000

__device__ __forceinline__ int4 pack_map(int s0, int s1, float w0, float w1) {
    return make_int4(s0, s1, __float_as_int(w0), __float_as_int(w1));
}

// ---------------------------------------------------------------------------
// Kernel 1: build the inverse map. Scattered 16B writes, ~9.2 MB total.
__global__ __launch_bounds__(256)
void build_map_kernel(const float* __restrict__ w,
                      const int*   __restrict__ old_idx,
                      const int*   __restrict__ new_idx,
                      const int*   __restrict__ new_left,
                      const int*   __restrict__ new_right,
                      int4*        __restrict__ map) {
    const int b = blockIdx.y;
    const int t = blockIdx.x * blockDim.x + threadIdx.x;
    if (t >= T_PER_B) return;

    int4* mb = map + (size_t)b * E_NEW_;

    if (t < U_) {
        const int u   = t;
        const int jl  = old_idx [b * E_OLD_ + u];
        const int jr  = old_idx [b * E_OLD_ + U_ + u];
        const int jn  = new_idx [b * U_ + u];
        const int jnl = new_left [b * U_ + u];
        const int jnr = new_right[b * U_ + u];

        const float* wp = w + ((size_t)b * U_ + u) * 6;
        const float lw0 = wp[0], lw1 = wp[1], lw2 = wp[2];
        const float rw0 = wp[3], rw1 = wp[4], rw2 = wp[5];

        mb[jl]  = pack_map(u,       u,       lw0,        0.f);
        mb[jnl] = pack_map(u,       u,       lw1,        0.f);
        mb[jr]  = pack_map(U_ + u,  U_ + u,  rw0,        0.f);
        mb[jnr] = pack_map(U_ + u,  U_ + u,  rw1,        0.f);
        mb[jn]  = pack_map(u,       U_ + u,  0.5f * lw2, 0.5f * rw2);
    } else {
        const int e = t + U_;  // [2U, E_OLD)
        const int j = old_idx[b * E_OLD_ + e];
        mb[j] = pack_map(e, e, 1.0f, 0.f);
    }
}

// ---------------------------------------------------------------------------
// Kernel 2: 64x64 LDS-tiled transpose feat[b][c][e] -> featT[bl][e][c].
// 256 B global segments both sides; +1 pad -> conflict-free LDS (addr mod 32
// = c_local + e_local pattern, 2-way max which is free on CDNA4).
constexpr int TT = 64;

__global__ __launch_bounds__(256)
void transpose_kernel(const float* __restrict__ feat,
                      float*       __restrict__ featT,
                      int b0) {
    __shared__ float tile[TT][TT + 1];   // 16.64 KB -> ~9 blocks/CU
    const int bl = blockIdx.z;           // local batch (featT index)
    const int b  = b0 + bl;              // global batch (feat index)
    const int e0 = blockIdx.x * TT;      // 750 tiles
    const int c0 = blockIdx.y * TT;      // 2 tiles (C=128)
    const int t  = threadIdx.x;
    const int lx = t & 63;               // within-wave contiguous index
    const int ly = t >> 6;               // 0..3

    // Load: lanes sweep e (contiguous 256 B per row), 4 c-rows per instr set.
    const float* fb = feat + (size_t)b * C_ * E_OLD_ + e0 + lx;
    #pragma unroll
    for (int i = 0; i < 16; ++i) {
        const int cl = ly * 16 + i;                       // c_local 0..63
        tile[cl][lx] = fb[(size_t)(c0 + cl) * E_OLD_];
    }
    __syncthreads();

    // Store: lanes sweep c (contiguous 256 B per row), 4 e-rows per instr set.
    float* ft = featT + (size_t)bl * E_OLD_ * C_ + c0 + lx;
    #pragma unroll
    for (int i = 0; i < 16; ++i) {
        const int el = ly * 16 + i;                       // e_local 0..63
        ft[(size_t)(e0 + el) * C_] = tile[lx][el];
    }
}

// ---------------------------------------------------------------------------
// Kernel 3: transposed gather. Block = 256 threads, tile = 64 output columns
// x 128 channels, staged through LDS in TWO 64-channel halves (17.4 KB).
//
// Phase A (all threads up front): 4 threads per column j; thread (j, cq) reads
// featT[s0][cq*32..+31] as 8x dwordx4 (contiguous 128 B -> 64 B line-granular
// L2 requests after 4-lane coalescing), FMAs w0/w1 (second row only for the
// U/E_NEW = 11% two-source columns), keeps acc[8] in registers.
// Then per half h: quadrants {2h, 2h+1} write their acc to LDS; barrier; all
// 256 threads store the half: lanes span j=0..63 for one c -> 256 B coalesced
// nontemporal stores (out is write-once; don't evict featT from L2).
constexpr int JT = 64;
constexpr int TILES_PER_B = E_NEW_ / JT;   // 1125 exactly, no tail

__global__ __launch_bounds__(256)
void gatherT_kernel(const float* __restrict__ featT,
                    const int4*  __restrict__ map,
                    float*       __restrict__ out,
                    int b0, int nb) {
    __shared__ float tile[JT][68];         // 64*68*4 = 17.4 KB -> ~8 blocks/CU
    const int bl    = blockIdx.x % nb;     // local batch (featT index)
    const int b     = b0 + bl;             // global batch (map/out index)
    const int chunk = blockIdx.x / nb;
    const int j0    = chunk * JT;
    const int t     = threadIdx.x;

    const int j  = t >> 2;                 // 0..63
    const int cq = t & 3;                  // c-quadrant (32 channels each)

    // ---- Phase A: gather rows -> registers -------------------------------
    const int4 m = map[(size_t)b * E_NEW_ + j0 + j];
    const float w0 = __int_as_float(m.z);
    const float w1 = __int_as_float(m.w);

    const float* fTb = featT + (size_t)bl * E_OLD_ * C_;
    const float4* r0 = (const float4*)(fTb + (size_t)m.x * C_) + cq * 8;

    float4 acc[8];
    #pragma unroll
    for (int i = 0; i < 8; ++i) {
        const float4 f = r0[i];
        acc[i].x = w0 * f.x;
        acc[i].y = w0 * f.y;
        acc[i].z = w0 * f.z;
        acc[i].w = w0 * f.w;
    }
    if (w1 != 0.f) {                       // 11% of columns
        const float4* r1 = (const float4*)(fTb + (size_t)m.y * C_) + cq * 8;
        #pragma unroll
        for (int i = 0; i < 8; ++i) {
            const float4 f = r1[i];
            acc[i].x += w1 * f.x;
            acc[i].y += w1 * f.y;
            acc[i].z += w1 * f.z;
            acc[i].w += w1 * f.w;
        }
    }

    // ---- Stage + store, one 64-channel half at a time --------------------
    const int jj = t & 63;
    const int q  = t >> 6;                 // 0..3 (16 channels each in a half)

    #pragma unroll
    for (int h = 0; h < 2; ++h) {
        if ((cq >> 1) == h) {
            float* trow = &tile[j][(cq & 1) * 32];   // 16B-aligned (272B rows)
            #pragma unroll
            for (int i = 0; i < 8; ++i)
                *(float4*)(trow + 4 * i) = acc[i];
        }
        __syncthreads();
        {
            const float* tr = &tile[jj][q * 16];
            float* ob = out + (size_t)b * C_ * E_NEW_
                            + (size_t)(h * 64 + q * 16) * E_NEW_ + j0 + jj;
            #pragma unroll
            for (int k = 0; k < 16; ++k)
                __builtin_nontemporal_store(tr[k], ob + (size_t)k * E_NEW_);
        }
        if (h == 0) __syncthreads();       // protect tile reuse by half 1
    }
}

// ---------------------------------------------------------------------------
// Fallback (R2 kernel): direct strided gather, used only if ws is too small
// for even a single-batch featT.
constexpr int K2_BLOCK     = 256;
constexpr int CHUNKS_PER_B = (E_NEW_ + K2_BLOCK - 1) / K2_BLOCK;  // 282

__global__ __launch_bounds__(K2_BLOCK)
void gather_kernel(const float* __restrict__ feat,
                   const int4*  __restrict__ map,
                   float*       __restrict__ out) {
    const int b     = blockIdx.x % B_;
    const int chunk = blockIdx.x / B_;
    const int j     = chunk * K2_BLOCK + threadIdx.x;
    if (j >= E_NEW_) return;

    const int4 m  = map[(size_t)b * E_NEW_ + j];
    const int  s0 = m.x;
    const int  s1 = m.y;
    const float w0 = __int_as_float(m.z);
    const float w1 = __int_as_float(m.w);

    const float* fb = feat + (size_t)b * C_ * E_OLD_;
    float*       ob = out  + (size_t)b * C_ * E_NEW_ + j;

    #pragma unroll 4
    for (int c = 0; c < C_; ++c) {
        const float f0 = fb[s0];
        const float f1 = fb[s1];
        *ob = w0 * f0 + w1 * f1;
        fb += E_OLD_;
        ob += E_NEW_;
    }
}

// ---------------------------------------------------------------------------
extern "C" void kernel_launch(void* const* d_in, const int* in_sizes, int n_in,
                              void* d_out, int out_size, void* d_ws, size_t ws_size,
                              hipStream_t stream) {
    const float* feat      = (const float*)d_in[0];
    const float* w         = (const float*)d_in[1];
    const int*   old_idx   = (const int*)  d_in[2];
    // d_in[3] = left_idx  (== old_idx[:, :U])   — unused
    // d_in[4] = right_idx (== old_idx[:, U:2U]) — unused
    const int*   new_idx   = (const int*)  d_in[5];
    const int*   new_left  = (const int*)  d_in[6];
    const int*   new_right = (const int*)  d_in[7];
    float*       out       = (float*)d_out;

    int4* map = (int4*)d_ws;                                   // 9.216 MB
    const size_t map_bytes = (size_t)B_ * E_NEW_ * sizeof(int4);
    const size_t featT_off = (map_bytes + 255) & ~(size_t)255;
    const size_t featT_one = (size_t)E_OLD_ * C_ * sizeof(float);   // 24.58 MB
    const size_t featT_all = (size_t)B_ * featT_one;                // 196.6 MB
    float* featT = (float*)((char*)d_ws + featT_off);

    {
        dim3 block(256);
        dim3 grid((T_PER_B + 255) / 256, B_);
        build_map_kernel<<<grid, block, 0, stream>>>(
            w, old_idx, new_idx, new_left, new_right, map);
    }

    if (ws_size >= featT_off + featT_all) {
        // Full-batch path: one transpose, one gather.
        {
            dim3 block(256);
            dim3 grid(E_OLD_ / TT, C_ / TT, B_);
            transpose_kernel<<<grid, block, 0, stream>>>(feat, featT, 0);
        }
        {
            dim3 block(256);
            dim3 grid(TILES_PER_B * B_);
            gatherT_kernel<<<grid, block, 0, stream>>>(featT, map, out, 0, B_);
        }
    } else if (ws_size >= featT_off + featT_one) {
        // Per-batch loop reusing one featT slab (stream-serialized).
        for (int b = 0; b < B_; ++b) {
            dim3 tblock(256);
            dim3 tgrid(E_OLD_ / TT, C_ / TT, 1);
            transpose_kernel<<<tgrid, tblock, 0, stream>>>(feat, featT, b);
            dim3 gblock(256);
            dim3 ggrid(TILES_PER_B);
            gatherT_kernel<<<ggrid, gblock, 0, stream>>>(featT, map, out, b, 1);
        }
    } else {
        // Workspace too small for any featT: R2 direct gather.
        dim3 block(K2_BLOCK);
        dim3 grid(CHUNKS_PER_B * B_);
        gather_kernel<<<grid, block, 0, stream>>>(feat, map, out);
    }
}

// Round 3
// 558.752 us; speedup vs baseline: 1.0146x; 1.0146x over previous
//
#include <hip/hip_runtime.h>

// MeshUnpool — transposed-gather formulation, v4.
//
// History: R2 direct gather request-rate-bound (147M scattered 4B loads,
// 1.79 TB/s, 682 us). v2: transpose feat -> featT[b][e][c] + row-gather +
// LDS-transposed coalesced stores -> 550 us total. v3 (two-half staging,
// NT stores, 64x64 transpose): 567 us — half-staging barrier regressed.
// ~290 us of dur is harness-constant (1.18 GB ws poison fill @181 us + resets).
//
// v4 changes:
//  - transpose: 128e x 64c tile, float4 lane loads -> 512 B read segments
//    (was 256 B) on the 192KB-strided read side; float4 stores (256 B
//    half-row segments, full 64B lines); LDS [128][65] -> 2-way (free)
//    bank aliasing, 33.3 KB, 4 blocks/CU.
//  - gatherT: revert to v2 single-stage structure (one barrier). Fix the
//    latent 8-way Phase-B bank conflict: pad 132 -> 133 words (row stride
//    533*4 B, odd mod 32 -> 2-way free); all LDS access scalar (133 breaks
//    16B alignment; LDS instr count irrelevant vs global latency).
//    Keep nontemporal out stores (write-once; preserve featT residency).
//
// Pipeline:
//   K1 build_map   : per-output-column {s0, s1, w0, w1}        (~9.2 MB ws)
//   K2 transpose   : feat[b][c][e] -> featT[b][e][c]           (ws)
//   K3 gatherT     : out[b][c][j] = w0*featT[b][s0][c] + w1*featT[b][s1][c]
// ws fallback: per-batch featT loop (24.6 MB), else R2 direct gather.

constexpr int B_     = 8;
constexpr int C_     = 128;
constexpr int E_OLD_ = 48000;
constexpr int U_     = 8000;
constexpr int E_NEW_ = E_OLD_ + 3 * U_;          // 72000
constexpr int T_PER_B = U_ + (E_OLD_ - 2 * U_);  // 40000

__device__ __forceinline__ int4 pack_map(int s0, int s1, float w0, float w1) {
    return make_int4(s0, s1, __float_as_int(w0), __float_as_int(w1));
}

// ---------------------------------------------------------------------------
// Kernel 1: build the inverse map. Scattered 16B writes, ~9.2 MB total.
__global__ __launch_bounds__(256)
void build_map_kernel(const float* __restrict__ w,
                      const int*   __restrict__ old_idx,
                      const int*   __restrict__ new_idx,
                      const int*   __restrict__ new_left,
                      const int*   __restrict__ new_right,
                      int4*        __restrict__ map) {
    const int b = blockIdx.y;
    const int t = blockIdx.x * blockDim.x + threadIdx.x;
    if (t >= T_PER_B) return;

    int4* mb = map + (size_t)b * E_NEW_;

    if (t < U_) {
        const int u   = t;
        const int jl  = old_idx [b * E_OLD_ + u];
        const int jr  = old_idx [b * E_OLD_ + U_ + u];
        const int jn  = new_idx [b * U_ + u];
        const int jnl = new_left [b * U_ + u];
        const int jnr = new_right[b * U_ + u];

        const float* wp = w + ((size_t)b * U_ + u) * 6;
        const float lw0 = wp[0], lw1 = wp[1], lw2 = wp[2];
        const float rw0 = wp[3], rw1 = wp[4], rw2 = wp[5];

        mb[jl]  = pack_map(u,       u,       lw0,        0.f);
        mb[jnl] = pack_map(u,       u,       lw1,        0.f);
        mb[jr]  = pack_map(U_ + u,  U_ + u,  rw0,        0.f);
        mb[jnr] = pack_map(U_ + u,  U_ + u,  rw1,        0.f);
        mb[jn]  = pack_map(u,       U_ + u,  0.5f * lw2, 0.5f * rw2);
    } else {
        const int e = t + U_;  // [2U, E_OLD)
        const int j = old_idx[b * E_OLD_ + e];
        mb[j] = pack_map(e, e, 1.0f, 0.f);
    }
}

// ---------------------------------------------------------------------------
// Kernel 2: transpose feat[b][c][e] -> featT[bl][e][c].
// Tile = 128 e x 64 c. Loads: 32-lane group sweeps 128 e as float4 ->
// 512 B segments per c-row (the strided side). Stores: 16-lane group sweeps
// 64 c as float4 -> 256 B segments (full 64B lines, dense region).
// LDS [128][65]: word-stride 65 === 1 (mod 32) -> <=2-way aliasing (free).
constexpr int TE = 128;
constexpr int TC = 64;

__global__ __launch_bounds__(256)
void transpose_kernel(const float* __restrict__ feat,
                      float*       __restrict__ featT,
                      int b0) {
    __shared__ float tile[TE][TC + 1];   // 33.28 KB -> 4 blocks/CU
    const int bl = blockIdx.z;           // local batch (featT index)
    const int b  = b0 + bl;              // global batch (feat index)
    const int e0 = blockIdx.x * TE;      // 375 tiles
    const int c0 = blockIdx.y * TC;      // 2 c-halves
    const int t  = threadIdx.x;

    // Load phase: 8 sweeps x 8 c-rows; lanes (t&31) cover e 0..127 as float4.
    {
        const int eo = (t & 31) * 4;
        const int co = t >> 5;           // 0..7
        const float* fb = feat + (size_t)b * C_ * E_OLD_ + e0 + eo;
        #pragma unroll
        for (int i = 0; i < 8; ++i) {
            const int c = i * 8 + co;
            const float4 v = *(const float4*)(fb + (size_t)(c0 + c) * E_OLD_);
            tile[eo + 0][c] = v.x;
            tile[eo + 1][c] = v.y;
            tile[eo + 2][c] = v.z;
            tile[eo + 3][c] = v.w;
        }
    }
    __syncthreads();

    // Store phase: 8 sweeps x 16 e-rows; lanes (t&15) cover c 0..63 as float4.
    {
        const int c4 = (t & 15) * 4;
        const int eb = t >> 4;           // 0..15
        float* ft = featT + (size_t)bl * E_OLD_ * C_
                          + (size_t)e0 * C_ + c0 + c4;
        #pragma unroll
        for (int i = 0; i < 8; ++i) {
            const int e = i * 16 + eb;
            float4 v;
            v.x = tile[e][c4 + 0];
            v.y = tile[e][c4 + 1];
            v.z = tile[e][c4 + 2];
            v.w = tile[e][c4 + 3];
            *(float4*)(ft + (size_t)e * C_) = v;
        }
    }
}

// ---------------------------------------------------------------------------
// Kernel 3: transposed gather (v2 structure). Block = 256 threads,
// tile = 64 output columns x 128 channels.
// Phase A: 4 threads per column j; thread (j, cq) reads featT[s0][cq*32..+31]
//          as 8x dwordx4 (128 B contiguous per thread), FMAs w0/w1 (second
//          row only for the 11% dual-source columns), stages to LDS.
// Phase B: thread (jj, cg) reads tile[jj][cg*32..+31], nontemporal-stores
//          out[b][c][j0+jj]; lanes span jj=0..63 -> 256 B coalesced segments.
// LDS pad = 133 words (stride === 5 mod 32, odd): Phase-B lane sweep over jj
// is 2-way (free) instead of 8-way at pad 132. All LDS access scalar.
constexpr int JT = 64;
constexpr int TILES_PER_B = E_NEW_ / JT;   // 1125 exactly, no tail

__global__ __launch_bounds__(256)
void gatherT_kernel(const float* __restrict__ featT,
                    const int4*  __restrict__ map,
                    float*       __restrict__ out,
                    int b0, int nb) {
    __shared__ float tile[JT][133];        // 34.05 KB -> 4 blocks/CU
    const int bl    = blockIdx.x % nb;     // local batch (featT index)
    const int b     = b0 + bl;             // global batch (map/out index)
    const int chunk = blockIdx.x / nb;
    const int j0    = chunk * JT;
    const int t     = threadIdx.x;

    // ---- Phase A: gather rows -> registers -> LDS ------------------------
    {
        const int j  = t >> 2;             // 0..63
        const int cq = t & 3;              // c-quadrant (32 channels each)
        const int4 m = map[(size_t)b * E_NEW_ + j0 + j];
        const float w0 = __int_as_float(m.z);
        const float w1 = __int_as_float(m.w);

        const float* fTb = featT + (size_t)bl * E_OLD_ * C_;
        const float4* r0 = (const float4*)(fTb + (size_t)m.x * C_) + cq * 8;

        float4 acc[8];
        #pragma unroll
        for (int i = 0; i < 8; ++i) {
            const float4 f = r0[i];
            acc[i].x = w0 * f.x;
            acc[i].y = w0 * f.y;
            acc[i].z = w0 * f.z;
            acc[i].w = w0 * f.w;
        }
        if (w1 != 0.f) {                   // 11% of columns
            const float4* r1 = (const float4*)(fTb + (size_t)m.y * C_) + cq * 8;
            #pragma unroll
            for (int i = 0; i < 8; ++i) {
                const float4 f = r1[i];
                acc[i].x += w1 * f.x;
                acc[i].y += w1 * f.y;
                acc[i].z += w1 * f.z;
                acc[i].w += w1 * f.w;
            }
        }
        float* trow = &tile[j][cq * 32];
        #pragma unroll
        for (int i = 0; i < 8; ++i) {
            trow[4 * i + 0] = acc[i].x;
            trow[4 * i + 1] = acc[i].y;
            trow[4 * i + 2] = acc[i].z;
            trow[4 * i + 3] = acc[i].w;
        }
    }
    __syncthreads();

    // ---- Phase B: LDS tile -> coalesced nontemporal stores ---------------
    {
        const int jj = t & 63;             // 0..63
        const int cg = t >> 6;             // 0..3
        const float* tr = &tile[jj][cg * 32];
        float* ob = out + (size_t)b * C_ * E_NEW_
                        + (size_t)(cg * 32) * E_NEW_ + j0 + jj;
        #pragma unroll
        for (int k = 0; k < 32; ++k)
            __builtin_nontemporal_store(tr[k], ob + (size_t)k * E_NEW_);
    }
}

// ---------------------------------------------------------------------------
// Fallback (R2 kernel): direct strided gather, used only if ws is too small
// for even a single-batch featT.
constexpr int K2_BLOCK     = 256;
constexpr int CHUNKS_PER_B = (E_NEW_ + K2_BLOCK - 1) / K2_BLOCK;  // 282

__global__ __launch_bounds__(K2_BLOCK)
void gather_kernel(const float* __restrict__ feat,
                   const int4*  __restrict__ map,
                   float*       __restrict__ out) {
    const int b     = blockIdx.x % B_;
    const int chunk = blockIdx.x / B_;
    const int j     = chunk * K2_BLOCK + threadIdx.x;
    if (j >= E_NEW_) return;

    const int4 m  = map[(size_t)b * E_NEW_ + j];
    const int  s0 = m.x;
    const int  s1 = m.y;
    const float w0 = __int_as_float(m.z);
    const float w1 = __int_as_float(m.w);

    const float* fb = feat + (size_t)b * C_ * E_OLD_;
    float*       ob = out  + (size_t)b * C_ * E_NEW_ + j;

    #pragma unroll 4
    for (int c = 0; c < C_; ++c) {
        const float f0 = fb[s0];
        const float f1 = fb[s1];
        *ob = w0 * f0 + w1 * f1;
        fb += E_OLD_;
        ob += E_NEW_;
    }
}

// ---------------------------------------------------------------------------
extern "C" void kernel_launch(void* const* d_in, const int* in_sizes, int n_in,
                              void* d_out, int out_size, void* d_ws, size_t ws_size,
                              hipStream_t stream) {
    const float* feat      = (const float*)d_in[0];
    const float* w         = (const float*)d_in[1];
    const int*   old_idx   = (const int*)  d_in[2];
    // d_in[3] = left_idx  (== old_idx[:, :U])   — unused
    // d_in[4] = right_idx (== old_idx[:, U:2U]) — unused
    const int*   new_idx   = (const int*)  d_in[5];
    const int*   new_left  = (const int*)  d_in[6];
    const int*   new_right = (const int*)  d_in[7];
    float*       out       = (float*)d_out;

    int4* map = (int4*)d_ws;                                   // 9.216 MB
    const size_t map_bytes = (size_t)B_ * E_NEW_ * sizeof(int4);
    const size_t featT_off = (map_bytes + 255) & ~(size_t)255;
    const size_t featT_one = (size_t)E_OLD_ * C_ * sizeof(float);   // 24.58 MB
    const size_t featT_all = (size_t)B_ * featT_one;                // 196.6 MB
    float* featT = (float*)((char*)d_ws + featT_off);

    {
        dim3 block(256);
        dim3 grid((T_PER_B + 255) / 256, B_);
        build_map_kernel<<<grid, block, 0, stream>>>(
            w, old_idx, new_idx, new_left, new_right, map);
    }

    if (ws_size >= featT_off + featT_all) {
        // Full-batch path: one transpose, one gather.
        {
            dim3 block(256);
            dim3 grid(E_OLD_ / TE, C_ / TC, B_);
            transpose_kernel<<<grid, block, 0, stream>>>(feat, featT, 0);
        }
        {
            dim3 block(256);
            dim3 grid(TILES_PER_B * B_);
            gatherT_kernel<<<grid, block, 0, stream>>>(featT, map, out, 0, B_);
        }
    } else if (ws_size >= featT_off + featT_one) {
        // Per-batch loop reusing one featT slab (stream-serialized).
        for (int b = 0; b < B_; ++b) {
            dim3 tblock(256);
            dim3 tgrid(E_OLD_ / TE, C_ / TC, 1);
            transpose_kernel<<<tgrid, tblock, 0, stream>>>(feat, featT, b);
            dim3 gblock(256);
            dim3 ggrid(TILES_PER_B);
            gatherT_kernel<<<ggrid, gblock, 0, stream>>>(featT, map, out, b, 1);
        }
    } else {
        // Workspace too small for any featT: R2 direct gather.
        dim3 block(K2_BLOCK);
        dim3 grid(CHUNKS_PER_B * B_);
        gather_kernel<<<grid, block, 0, stream>>>(feat, map, out);
    }
}

// Round 4
// 526.266 us; speedup vs baseline: 1.0772x; 1.0617x over previous
//
#include <hip/hip_runtime.h>

// MeshUnpool — transposed-gather, v5: batch-pipelined launches.
//
// History: R2 direct gather request-rate-bound (147M scattered 4B loads,
// 1.79 TB/s, 682 us). v2: transpose feat -> featT[b][e][c] + row-gather +
// LDS-transposed coalesced out stores -> 550 us. v3/v4 micro-tuning (bank
// pads, 512B transpose segments, NT stores): 567/559 us — all within noise.
// Conclusion: intra-kernel tuning exhausted; remaining slack is the SERIAL
// transpose -> gather structure. ~290 us of dur is harness-constant
// (1.18 GB ws poison fill @181 us + resets).
//
// v5: software-pipeline across batches. Step k (one launch) runs
//   transpose(batch k)   [blocks 0..749]        — BW-streaming
//   gather(batch k-1)    [blocks 750..1874]     — latency-bound
// concurrently in one grid; the launch boundary gives transpose(k) ->
// gather(k) ordering for free. build_map rides along in step 0 (extra 1250
// blocks). Complementary profiles (streaming vs latency) share the CUs.
// 9 launches total; expected ~40-60 us saved vs serial.
//
// ws fallback: per-batch featT loop (24.6 MB), else R2 direct gather.

constexpr int B_     = 8;
constexpr int C_     = 128;
constexpr int E_OLD_ = 48000;
constexpr int U_     = 8000;
constexpr int E_NEW_ = E_OLD_ + 3 * U_;          // 72000
constexpr int T_PER_B = U_ + (E_OLD_ - 2 * U_);  // 40000

constexpr int TE = 128;                          // transpose tile: e extent
constexpr int TC = 64;                           // transpose tile: c extent
constexpr int JT = 64;                           // gather tile: j extent

constexpr int T_BLOCKS    = (E_OLD_ / TE) * (C_ / TC);       // 750
constexpr int G_BLOCKS    = E_NEW_ / JT;                     // 1125 (no tail)
constexpr int BM_BLOCKS   = (B_ * T_PER_B + 255) / 256;      // 1250

// LDS: union of transpose tile [128][65] (8320 w) and gather tile [64][133]
// (8512 w) -> 34.05 KB, 4 blocks/CU in all roles.
constexpr int LDS_WORDS = 64 * 133;

__device__ __forceinline__ int4 pack_map(int s0, int s1, float w0, float w1) {
    return make_int4(s0, s1, __float_as_int(w0), __float_as_int(w1));
}

// ---------------------------------------------------------------------------
// Role bodies (shared by pipelined and fallback kernels).

__device__ __forceinline__ void build_body(
    const float* __restrict__ w,
    const int*   __restrict__ old_idx,
    const int*   __restrict__ new_idx,
    const int*   __restrict__ new_left,
    const int*   __restrict__ new_right,
    int4*        __restrict__ map,
    int b, int t) {
    int4* mb = map + (size_t)b * E_NEW_;

    if (t < U_) {
        const int u   = t;
        const int jl  = old_idx [b * E_OLD_ + u];
        const int jr  = old_idx [b * E_OLD_ + U_ + u];
        const int jn  = new_idx [b * U_ + u];
        const int jnl = new_left [b * U_ + u];
        const int jnr = new_right[b * U_ + u];

        const float* wp = w + ((size_t)b * U_ + u) * 6;
        const float lw0 = wp[0], lw1 = wp[1], lw2 = wp[2];
        const float rw0 = wp[3], rw1 = wp[4], rw2 = wp[5];

        mb[jl]  = pack_map(u,       u,       lw0,        0.f);
        mb[jnl] = pack_map(u,       u,       lw1,        0.f);
        mb[jr]  = pack_map(U_ + u,  U_ + u,  rw0,        0.f);
        mb[jnr] = pack_map(U_ + u,  U_ + u,  rw1,        0.f);
        mb[jn]  = pack_map(u,       U_ + u,  0.5f * lw2, 0.5f * rw2);
    } else {
        const int e = t + U_;  // [2U, E_OLD)
        const int j = old_idx[b * E_OLD_ + e];
        mb[j] = pack_map(e, e, 1.0f, 0.f);
    }
}

// Transpose one 128e x 64c tile of feat[b] into featT[bl].
// Loads: 32-lane groups sweep e as float4 -> 512 B segments on the strided
// side. Stores: float4 -> 256 B segments. LDS stride 65 === 1 mod 32 -> free.
__device__ __forceinline__ void transpose_body(
    const float* __restrict__ feat,
    float*       __restrict__ featT,
    int b, int bl, int tileIdx, int t,
    float* __restrict__ tile /* [128*65] */) {
    const int e0 = (tileIdx >> 1) * TE;
    const int c0 = (tileIdx & 1) * TC;

    {
        const int eo = (t & 31) * 4;
        const int co = t >> 5;           // 0..7
        const float* fb = feat + (size_t)b * C_ * E_OLD_ + e0 + eo;
        #pragma unroll
        for (int i = 0; i < 8; ++i) {
            const int c = i * 8 + co;
            const float4 v = *(const float4*)(fb + (size_t)(c0 + c) * E_OLD_);
            tile[(eo + 0) * 65 + c] = v.x;
            tile[(eo + 1) * 65 + c] = v.y;
            tile[(eo + 2) * 65 + c] = v.z;
            tile[(eo + 3) * 65 + c] = v.w;
        }
    }
    __syncthreads();
    {
        const int c4 = (t & 15) * 4;
        const int eb = t >> 4;           // 0..15
        float* ft = featT + (size_t)bl * E_OLD_ * C_
                          + (size_t)e0 * C_ + c0 + c4;
        #pragma unroll
        for (int i = 0; i < 8; ++i) {
            const int e = i * 16 + eb;
            float4 v;
            v.x = tile[e * 65 + c4 + 0];
            v.y = tile[e * 65 + c4 + 1];
            v.z = tile[e * 65 + c4 + 2];
            v.w = tile[e * 65 + c4 + 3];
            *(float4*)(ft + (size_t)e * C_) = v;
        }
    }
}

// Gather one 64j x 128c tile: out[b][c][j] = w0*featT[bl][s0][c] +
// w1*featT[bl][s1][c]. Phase A: 4 threads/column read 128 B contiguous row
// chunks (dual row only for the 11% two-source columns). Phase B: LDS
// transpose -> 256 B coalesced nontemporal stores (out is write-once).
// LDS stride 133 === 5 mod 32 (odd) -> Phase-B lane sweep 2-way (free).
__device__ __forceinline__ void gather_body(
    const float* __restrict__ featT,
    const int4*  __restrict__ map,
    float*       __restrict__ out,
    int b, int bl, int chunk, int t,
    float* __restrict__ tile /* [64*133] */) {
    const int j0 = chunk * JT;

    {
        const int j  = t >> 2;             // 0..63
        const int cq = t & 3;              // c-quadrant (32 channels)
        const int4 m = map[(size_t)b * E_NEW_ + j0 + j];
        const float w0 = __int_as_float(m.z);
        const float w1 = __int_as_float(m.w);

        const float* fTb = featT + (size_t)bl * E_OLD_ * C_;
        const float4* r0 = (const float4*)(fTb + (size_t)m.x * C_) + cq * 8;

        float4 acc[8];
        #pragma unroll
        for (int i = 0; i < 8; ++i) {
            const float4 f = r0[i];
            acc[i].x = w0 * f.x;
            acc[i].y = w0 * f.y;
            acc[i].z = w0 * f.z;
            acc[i].w = w0 * f.w;
        }
        if (w1 != 0.f) {                   // 11% of columns
            const float4* r1 = (const float4*)(fTb + (size_t)m.y * C_) + cq * 8;
            #pragma unroll
            for (int i = 0; i < 8; ++i) {
                const float4 f = r1[i];
                acc[i].x += w1 * f.x;
                acc[i].y += w1 * f.y;
                acc[i].z += w1 * f.z;
                acc[i].w += w1 * f.w;
            }
        }
        float* trow = tile + j * 133 + cq * 32;
        #pragma unroll
        for (int i = 0; i < 8; ++i) {
            trow[4 * i + 0] = acc[i].x;
            trow[4 * i + 1] = acc[i].y;
            trow[4 * i + 2] = acc[i].z;
            trow[4 * i + 3] = acc[i].w;
        }
    }
    __syncthreads();
    {
        const int jj = t & 63;             // 0..63
        const int cg = t >> 6;             // 0..3
        const float* tr = tile + jj * 133 + cg * 32;
        float* ob = out + (size_t)b * C_ * E_NEW_
                        + (size_t)(cg * 32) * E_NEW_ + j0 + jj;
        #pragma unroll
        for (int k = 0; k < 32; ++k)
            __builtin_nontemporal_store(tr[k], ob + (size_t)k * E_NEW_);
    }
}

// ---------------------------------------------------------------------------
// Pipelined step kernel: one launch = transpose(batch k) || gather(batch k-1)
// [|| build_map when k==0]. Launch boundary orders transpose(k)->gather(k).
__global__ __launch_bounds__(256)
void pipe_step_kernel(const float* __restrict__ feat,
                      float*       __restrict__ featT,
                      const float* __restrict__ w,
                      const int*   __restrict__ old_idx,
                      const int*   __restrict__ new_idx,
                      const int*   __restrict__ new_left,
                      const int*   __restrict__ new_right,
                      int4*        __restrict__ map,
                      float*       __restrict__ out,
                      int k) {
    __shared__ float lds[LDS_WORDS];
    int bid = blockIdx.x;
    const int t = threadIdx.x;

    if (bid < T_BLOCKS) {
        if (k < B_)
            transpose_body(feat, featT, k, k, bid, t, lds);
        return;
    }
    bid -= T_BLOCKS;
    if (bid < G_BLOCKS) {
        if (k >= 1)
            gather_body(featT, map, out, k - 1, k - 1, bid, t, lds);
        return;
    }
    bid -= G_BLOCKS;     // build role: present only in the k==0 grid
    const int tg = bid * 256 + t;
    if (tg < B_ * T_PER_B)
        build_body(w, old_idx, new_idx, new_left, new_right, map,
                   tg / T_PER_B, tg % T_PER_B);
}

// ---------------------------------------------------------------------------
// Standalone kernels for the ws-constrained fallback paths.
__global__ __launch_bounds__(256)
void build_map_kernel(const float* __restrict__ w,
                      const int*   __restrict__ old_idx,
                      const int*   __restrict__ new_idx,
                      const int*   __restrict__ new_left,
                      const int*   __restrict__ new_right,
                      int4*        __restrict__ map) {
    const int b = blockIdx.y;
    const int t = blockIdx.x * blockDim.x + threadIdx.x;
    if (t >= T_PER_B) return;
    build_body(w, old_idx, new_idx, new_left, new_right, map, b, t);
}

__global__ __launch_bounds__(256)
void transpose_kernel(const float* __restrict__ feat,
                      float*       __restrict__ featT,
                      int b0) {
    __shared__ float lds[TE * (TC + 1)];
    transpose_body(feat, featT, b0 + (int)blockIdx.z, (int)blockIdx.z,
                   (int)blockIdx.x, (int)threadIdx.x, lds);
}

__global__ __launch_bounds__(256)
void gatherT_kernel(const float* __restrict__ featT,
                    const int4*  __restrict__ map,
                    float*       __restrict__ out,
                    int b0, int nb) {
    __shared__ float lds[JT * 133];
    const int bl    = blockIdx.x % nb;
    const int chunk = blockIdx.x / nb;
    gather_body(featT, map, out, b0 + bl, bl, chunk, (int)threadIdx.x, lds);
}

// Fallback (R2 kernel): direct strided gather if ws can't hold any featT.
constexpr int K2_BLOCK     = 256;
constexpr int CHUNKS_PER_B = (E_NEW_ + K2_BLOCK - 1) / K2_BLOCK;  // 282

__global__ __launch_bounds__(K2_BLOCK)
void gather_kernel(const float* __restrict__ feat,
                   const int4*  __restrict__ map,
                   float*       __restrict__ out) {
    const int b     = blockIdx.x % B_;
    const int chunk = blockIdx.x / B_;
    const int j     = chunk * K2_BLOCK + threadIdx.x;
    if (j >= E_NEW_) return;

    const int4 m  = map[(size_t)b * E_NEW_ + j];
    const float w0 = __int_as_float(m.z);
    const float w1 = __int_as_float(m.w);

    const float* fb = feat + (size_t)b * C_ * E_OLD_;
    float*       ob = out  + (size_t)b * C_ * E_NEW_ + j;

    #pragma unroll 4
    for (int c = 0; c < C_; ++c) {
        const float f0 = fb[m.x];
        const float f1 = fb[m.y];
        *ob = w0 * f0 + w1 * f1;
        fb += E_OLD_;
        ob += E_NEW_;
    }
}

// ---------------------------------------------------------------------------
extern "C" void kernel_launch(void* const* d_in, const int* in_sizes, int n_in,
                              void* d_out, int out_size, void* d_ws, size_t ws_size,
                              hipStream_t stream) {
    const float* feat      = (const float*)d_in[0];
    const float* w         = (const float*)d_in[1];
    const int*   old_idx   = (const int*)  d_in[2];
    // d_in[3] = left_idx  (== old_idx[:, :U])   — unused
    // d_in[4] = right_idx (== old_idx[:, U:2U]) — unused
    const int*   new_idx   = (const int*)  d_in[5];
    const int*   new_left  = (const int*)  d_in[6];
    const int*   new_right = (const int*)  d_in[7];
    float*       out       = (float*)d_out;

    int4* map = (int4*)d_ws;                                   // 9.216 MB
    const size_t map_bytes = (size_t)B_ * E_NEW_ * sizeof(int4);
    const size_t featT_off = (map_bytes + 255) & ~(size_t)255;
    const size_t featT_one = (size_t)E_OLD_ * C_ * sizeof(float);   // 24.58 MB
    const size_t featT_all = (size_t)B_ * featT_one;                // 196.6 MB
    float* featT = (float*)((char*)d_ws + featT_off);

    if (ws_size >= featT_off + featT_all) {
        // Pipelined path: step k = transpose(k) || gather(k-1) [|| build @k=0].
        for (int k = 0; k <= B_; ++k) {
            const int grid = T_BLOCKS + G_BLOCKS + (k == 0 ? BM_BLOCKS : 0);
            pipe_step_kernel<<<dim3(grid), dim3(256), 0, stream>>>(
                feat, featT, w, old_idx, new_idx, new_left, new_right,
                map, out, k);
        }
    } else if (ws_size >= featT_off + featT_one) {
        // Per-batch loop reusing one featT slab (stream-serialized).
        {
            dim3 block(256);
            dim3 grid((T_PER_B + 255) / 256, B_);
            build_map_kernel<<<grid, block, 0, stream>>>(
                w, old_idx, new_idx, new_left, new_right, map);
        }
        for (int b = 0; b < B_; ++b) {
            transpose_kernel<<<dim3(T_BLOCKS, 1, 1), dim3(256), 0, stream>>>(
                feat, featT, b);
            gatherT_kernel<<<dim3(G_BLOCKS), dim3(256), 0, stream>>>(
                featT, map, out, b, 1);
        }
    } else {
        // Workspace too small for any featT: R2 direct gather.
        {
            dim3 block(256);
            dim3 grid((T_PER_B + 255) / 256, B_);
            build_map_kernel<<<grid, block, 0, stream>>>(
                w, old_idx, new_idx, new_left, new_right, map);
        }
        dim3 block(K2_BLOCK);
        dim3 grid(CHUNKS_PER_B * B_);
        gather_kernel<<<grid, block, 0, stream>>>(feat, map, out);
    }
}